// Round 16
// baseline (365.544 us; speedup 1.0000x reference)
//
#include <hip/hip_runtime.h>

#define B_    2
#define NSEQ  4096
#define DM    1024
#define H_    16
#define DH    64
#define MF    266
#define MP    288          // padded feature count, 9 x 32 (pads are zero)
#define NROWS (B_*NSEQ)    // 8192
#define NHROWS (B_*H_*NSEQ) // 131072
#define RATIO 0.06131393394849658f   // 266^-0.5
#define DNORM 0.3535533905932738f    // 64^-0.25
#define KEPS  1e-4f
#define CEPS  1e-6f
#define RKC   (RATIO*KEPS)

// chunked causal scan geometry
#define CH    128                 // tokens per chunk
#define NC    32                  // chunks per (b,h) = NSEQ/CH
#define SROW  (65*MP)             // logical per-chunk state elems (64 S rows + z row)
#define SELEM (64*MP)             // S elems per chunk (bf16)

#define AS1 __attribute__((address_space(1)))
#define AS3 __attribute__((address_space(3)))

typedef unsigned short u16;
typedef unsigned int   u32;

typedef __bf16 bf16x8 __attribute__((ext_vector_type(8)));
typedef float  f32x4  __attribute__((ext_vector_type(4)));

__device__ __forceinline__ float b2f(u16 u){ u32 x = ((u32)u) << 16; return __builtin_bit_cast(float, x); }
__device__ __forceinline__ u16 f2b(float f){
    return __builtin_bit_cast(u16, (__bf16)f);   // native RTNE cvt
}
__device__ __forceinline__ u32 enc_max(float f){ u32 b = __builtin_bit_cast(u32, f); return (b & 0x80000000u) ? ~b : (b | 0x80000000u); }
__device__ __forceinline__ float dec_max(u32 u){ u32 b = (u & 0x80000000u) ? (u & 0x7fffffffu) : ~u; return __builtin_bit_cast(float, b); }

// ---------------------------------------------------------------------------
// Per-input dtype detection, all 10 inputs in one launch. flag 1=bf16, 0=fp32.
// ---------------------------------------------------------------------------
struct DetectArgs { const u32* p[10]; int nw[10]; };

__global__ void detect_all(DetectArgs a, u32* __restrict__ flags)
{
    __shared__ int cnt[256];
    int k = blockIdx.x;
    const u32* src = a.p[k];
    int nwords = a.nw[k];
    int t = threadIdx.x; int c = 0;
    for (int i = t; i < nwords; i += 256) {
        u32 w = src[i];
        int ea = (int)((w >> 7)  & 0xFF);
        int eb = (int)((w >> 23) & 0xFF);
        c += (ea >= 112 && ea <= 143) ? 1 : 0;
        c += (eb >= 112 && eb <= 143) ? 1 : 0;
    }
    cnt[t] = c; __syncthreads();
    for (int s = 128; s; s >>= 1) { if (t < s) cnt[t] += cnt[t + s]; __syncthreads(); }
    if (t == 0) flags[k] = (cnt[0] >= (nwords * 3) / 2) ? 1u : 0u;  // 75% of 2*nwords
}

// ---------------------------------------------------------------------------
// Consolidated conversion: x, Wq/Wk/Wv/Wo, 4 biases, proj (+pad), gpart/gmax 0.
// ---------------------------------------------------------------------------
__device__ __forceinline__ void conv8(const void* src, u16* dst, int i, u32 flag)
{
    if (flag) {
        *(uint4*)(dst + i) = *(const uint4*)((const u16*)src + i);
    } else {
        const float* s = (const float*)src + i;
        u16 tmp[8];
        #pragma unroll
        for (int j = 0; j < 8; ++j) tmp[j] = f2b(s[j]);
        *(uint4*)(dst + i) = *(uint4*)tmp;
    }
}

struct ConvAllArgs {
    const void* xs;    u16* xd;
    const void* wsrc[4]; u16* wdst[4];   // Wq,Wk,Wv,Wo (flags 1,3,5,7)
    const void* bsrc[4]; u16* bdst[4];   // bq,bk,bv,bo (flags 2,4,6,8)
    const void* pj;    u16* pjd;
    u32* gpart; u32* gmax;
    const u32* flags;
};

// grid: 4096 (x) + 2048 (W) + 4 (bias) + 9 (proj) + 1 (misc) = 6158 blocks
__global__ __launch_bounds__(256)
void conv_all(ConvAllArgs a)
{
    int blk = blockIdx.x, t = threadIdx.x;
    if (blk < 4096) {
        int i = blk * 2048 + t * 8;
        conv8(a.xs, a.xd, i, a.flags[0]);
    } else if (blk < 6144) {
        int r = blk - 4096; int w = r >> 9; int i = (r & 511) * 2048 + t * 8;
        conv8(a.wsrc[w], a.wdst[w], i, a.flags[1 + 2*w]);
    } else if (blk < 6148) {
        int w = blk - 6144; int i = t * 8;
        if (i < DM) conv8(a.bsrc[w], a.bdst[w], i, a.flags[2 + 2*w]);
    } else if (blk < 6157) {
        int i = (blk - 6148) * 2048 + t * 8;   // < MP*DH = 18432
        if (i < MF * DH) conv8(a.pj, a.pjd, i, a.flags[9]);
        else             *(uint4*)(a.pjd + i) = (uint4){0,0,0,0};
    } else {
        a.gpart[t] = 0u;
        if (t == 0) *a.gmax = 0u;
    }
}

// ---------------------------------------------------------------------------
// GEMM body (m97 structure, BK=64): C[r][c] = sum_k A[r][k]*W[c][k].
// ---------------------------------------------------------------------------
#define GEMM_BODY(A_, Bm_, bm_, bn_, ACC_)                                    \
    const int K = DM;                                                          \
    __shared__ u16 As[128 * 64];                                               \
    __shared__ u16 Bs[128 * 64];                                               \
    int t = threadIdx.x;                                                       \
    int wave = t >> 6, lane = t & 63;                                          \
    int wm = wave >> 1, wn = wave & 1;                                         \
    int quad = lane >> 4, l16 = lane & 15;                                     \
    int rowc = lane >> 3;                                                      \
    int csrc = ((lane & 7) ^ rowc) * 8;                                        \
    int cA = wave * 4;                                                         \
    const u16* ap0 = A_  + (size_t)(bm_ + cA*8 + rowc) * K + csrc;             \
    const u16* bp0 = Bm_ + (size_t)(bn_ + cA*8 + rowc) * K + csrc;             \
    u16* lA = As + cA * 512;                                                   \
    u16* lB = Bs + cA * 512;                                                   \
    f32x4 ACC_[4][4];                                                          \
    _Pragma("unroll")                                                          \
    for (int i = 0; i < 4; ++i)                                                \
        _Pragma("unroll")                                                      \
        for (int j = 0; j < 4; ++j) ACC_[i][j] = (f32x4){0.f,0.f,0.f,0.f};     \
    for (int k0 = 0; k0 < K; k0 += 64) {                                       \
        _Pragma("unroll")                                                      \
        for (int j = 0; j < 4; ++j) {                                          \
            __builtin_amdgcn_global_load_lds((const AS1 void*)(ap0 + (size_t)j*8*K + k0), (AS3 void*)(lA + j*512), 16, 0, 0); \
            __builtin_amdgcn_global_load_lds((const AS1 void*)(bp0 + (size_t)j*8*K + k0), (AS3 void*)(lB + j*512), 16, 0, 0); \
        }                                                                      \
        __syncthreads();                                                       \
        _Pragma("unroll")                                                      \
        for (int ks = 0; ks < 2; ++ks) {                                       \
            bf16x8 af[4], bfr[4];                                              \
            int sw = ((((ks << 2) | quad) ^ (l16 & 7)) << 4);                  \
            _Pragma("unroll")                                                  \
            for (int i = 0; i < 4; ++i) {                                      \
                af[i]  = *(const bf16x8*)((const char*)As + (wm*64 + i*16 + l16)*128 + sw); \
                bfr[i] = *(const bf16x8*)((const char*)Bs + (wn*64 + i*16 + l16)*128 + sw); \
            }                                                                  \
            _Pragma("unroll")                                                  \
            for (int i = 0; i < 4; ++i)                                        \
                _Pragma("unroll")                                              \
                for (int j = 0; j < 4; ++j)                                    \
                    ACC_[i][j] = __builtin_amdgcn_mfma_f32_16x16x32_bf16(af[i], bfr[j], ACC_[i][j], 0, 0, 0); \
        }                                                                      \
        __syncthreads();                                                       \
    }

// QKV fused: 3D grid (64, 8, 3). z=0 -> V (bf16). z=1/2 -> Q/K written as
// DNORM-scaled hi/lo bf16 planes (the exact decomposition feat_qk needs).
__global__ __launch_bounds__(256)
void gemm_qkv(const u16* __restrict__ A,
              const u16* __restrict__ Wqb, const u16* __restrict__ Wkb,
              const u16* __restrict__ Wvb,
              const u16* __restrict__ bqb, const u16* __restrict__ bkb,
              const u16* __restrict__ bvb,
              u16* __restrict__ Vb,
              u16* __restrict__ Qh, u16* __restrict__ Ql,
              u16* __restrict__ Kh, u16* __restrict__ Kl)
{
    int z  = blockIdx.z;
    int bm = blockIdx.x * 128, bn = blockIdx.y * 128;

    const u16* Bm   = (z == 0) ? Wvb : (z == 1) ? Wqb : Wkb;
    const u16* bias = (z == 0) ? bvb : (z == 1) ? bqb : bkb;
    GEMM_BODY(A, Bm, bm, bn, acc)
    u16* Oh = (z == 1) ? Qh : Kh;
    u16* Ol = (z == 1) ? Ql : Kl;
    #pragma unroll
    for (int i = 0; i < 4; ++i) {
        #pragma unroll
        for (int j = 0; j < 4; ++j) {
            int col = bn + wn*64 + j*16 + l16;
            float bv = b2f(bias[col]);
            #pragma unroll
            for (int r = 0; r < 4; ++r) {
                int row = bm + wm*64 + i*16 + quad*4 + r;
                float v = acc[i][j][r] + bv;
                if (z == 0) {
                    Vb[(size_t)row * DM + col] = f2b(v);
                } else {
                    float vn = v * DNORM;
                    u16 hb = f2b(vn);
                    u16 lb = f2b(vn - b2f(hb));
                    Oh[(size_t)row * DM + col] = hb;
                    Ol[(size_t)row * DM + col] = lb;
                }
            }
        }
    }
}

// out-projection (fp32 output), 1D grid 512, XCD-bijective + 4x4 supergroup
__global__ __launch_bounds__(256)
void gemm_nt(const u16* __restrict__ A, const u16* __restrict__ Bm,
             const u16* __restrict__ bias, float* __restrict__ C)
{
    int bid = blockIdx.x;                 // 0..511
    int xcd = bid & 7, pos = bid >> 3;
    int q   = xcd * 64 + pos;             // contiguous logical range per XCD
    int idx = q & 15, sg = q >> 4;        // 32 supergroups of 4x4
    int sgm = sg & 15, sgn = sg >> 4;     // 16 m-supers, 2 n-supers
    int bm = (sgm*4 + (idx & 3)) * 128;
    int bn = (sgn*4 + (idx >> 2)) * 128;
    GEMM_BODY(A, Bm, bm, bn, acc)
    #pragma unroll
    for (int i = 0; i < 4; ++i) {
        #pragma unroll
        for (int j = 0; j < 4; ++j) {
            int col = bn + wn*64 + j*16 + l16;
            float bv = b2f(bias[col]);
            #pragma unroll
            for (int r = 0; r < 4; ++r) {
                int row = bm + wm*64 + i*16 + quad*4 + r;
                C[(size_t)row * DM + col] = acc[i][j][r] + bv;
            }
        }
    }
}

// ---------------------------------------------------------------------------
// Fused MFMA feature map, Q and K in one launch (grid 4096).
// Inputs are pre-split DNORM-scaled hi/lo bf16 planes (from gemm_qkv).
// T5: setprio(1) around the MFMA burst (independent blocks, role-split).
// ---------------------------------------------------------------------------
__global__ __launch_bounds__(256)
void feat_qk(const u16* __restrict__ Qhp, const u16* __restrict__ Qlp,
             const u16* __restrict__ Khp, const u16* __restrict__ Klp,
             const u16* __restrict__ projP, u16* __restrict__ Qp,
             u16* __restrict__ Kp, u32* __restrict__ gpart,
             float* __restrict__ lstab)
{
    int blk = blockIdx.x;             // 0..4095
    int isK = blk >> 11;
    int blk2 = blk & 2047;
    int bh = blk2 >> 6, nt = blk2 & 63;
    int b = bh >> 4, h = bh & 15;
    int n0 = nt * 64;
    int t = threadIdx.x;
    int lane = t & 63, w = t >> 6;
    int quad = lane >> 4, l16 = lane & 15;

    const u16* Xh = isK ? Khp : Qhp;
    const u16* Xl = isK ? Klp : Qlp;
    u16* OutP = isK ? Kp : Qp;

    __shared__ uint4 smemU[2368];     // max(proj 288*128B, out 64*296*2B) = 37888B
    __shared__ float red4[4];
    u16* smem16 = (u16*)smemU;

    size_t rbase = ((size_t)(b * NSEQ + n0 + w*16 + l16)) * DM + h * DH;
    bf16x8 ahi[2], alo[2];
    float sq = 0.f;
    #pragma unroll
    for (int ks = 0; ks < 2; ++ks) {
        uint4 hv = *(const uint4*)(Xh + rbase + ks*32 + quad*8);
        uint4 lv = *(const uint4*)(Xl + rbase + ks*32 + quad*8);
        ahi[ks] = __builtin_bit_cast(bf16x8, hv);
        alo[ks] = __builtin_bit_cast(bf16x8, lv);
        const u16* he = (const u16*)&hv;
        const u16* le = (const u16*)&lv;
        #pragma unroll
        for (int i = 0; i < 8; ++i) {
            float v = b2f(he[i]) + b2f(le[i]);
            sq += v * v;
        }
    }
    sq += __shfl_xor(sq, 16, 64);
    sq += __shfl_xor(sq, 32, 64);
    float diag_my = 0.5f * sq;

    // stage proj into LDS, XOR-swizzled: row m at byte m*128, byte^((m&7)<<4)
    for (int i = t; i < 2304; i += 256) {
        int m = i >> 3, c = i & 7;
        uint4 v = *(const uint4*)(projP + m*64 + c*8);
        int dstb = m*128 + ((c*16) ^ ((m & 7) << 4));
        *(uint4*)((char*)smemU + dstb) = v;
    }

    __syncthreads();                  // projS ready

    f32x4 acc[18];
    #pragma unroll
    for (int j = 0; j < 18; ++j) acc[j] = (f32x4){0.f,0.f,0.f,0.f};
    __builtin_amdgcn_s_setprio(1);
    #pragma unroll
    for (int j = 0; j < 18; ++j) {
        int m = j*16 + l16;
        #pragma unroll
        for (int ks = 0; ks < 2; ++ks) {
            int off = m*128 + (((quad*16) + ks*64) ^ ((m & 7) << 4));
            bf16x8 bf = *(const bf16x8*)((const char*)smemU + off);
            acc[j] = __builtin_amdgcn_mfma_f32_16x16x32_bf16(ahi[ks], bf, acc[j], 0, 0, 0);
            acc[j] = __builtin_amdgcn_mfma_f32_16x16x32_bf16(alo[ks], bf, acc[j], 0, 0, 0);
        }
    }
    __builtin_amdgcn_s_setprio(0);

    // per-row max over valid m: tiles 0..15 full; tile 16: l16<10; tile 17: pad
    float rmax[4];
    #pragma unroll
    for (int r = 0; r < 4; ++r) rmax[r] = -3.4e38f;
    #pragma unroll
    for (int j = 0; j < 16; ++j)
        #pragma unroll
        for (int r = 0; r < 4; ++r) rmax[r] = fmaxf(rmax[r], acc[j][r]);
    if (l16 < MF - 256) {
        #pragma unroll
        for (int r = 0; r < 4; ++r) rmax[r] = fmaxf(rmax[r], acc[16][r]);
    }
    #pragma unroll
    for (int s = 1; s < 16; s <<= 1)
        #pragma unroll
        for (int r = 0; r < 4; ++r)
            rmax[r] = fmaxf(rmax[r], __shfl_xor(rmax[r], s, 64));

    float stab_blk = 0.f;
    if (isK) {
        float wm2 = fmaxf(fmaxf(rmax[0], rmax[1]), fmaxf(rmax[2], rmax[3]));
        wm2 = fmaxf(wm2, __shfl_xor(wm2, 16, 64));
        wm2 = fmaxf(wm2, __shfl_xor(wm2, 32, 64));
        if (lane == 0) red4[w] = wm2;
        __syncthreads();
        stab_blk = fmaxf(fmaxf(red4[0], red4[1]), fmaxf(red4[2], red4[3]));
        if (t == 0) {
            atomicMax(&gpart[blk2 & 255], enc_max(stab_blk));
            lstab[blk2] = stab_blk;
        }
    }

    float dg[4];
    #pragma unroll
    for (int r = 0; r < 4; ++r) dg[r] = __shfl(diag_my, quad*4 + r, 64);

    __syncthreads();                  // all proj reads done; reuse LDS as outS

    #pragma unroll
    for (int j = 0; j < 18; ++j) {
        int m = j*16 + l16;
        #pragma unroll
        for (int r = 0; r < 4; ++r) {
            float stab = isK ? stab_blk : rmax[r];
            float ex = __expf(acc[j][r] - dg[r] - stab);
            float val = isK ? (RATIO * ex) : (RATIO * (ex + KEPS));
            u16 ov = (m < MF) ? f2b(val) : (u16)0;
            smem16[(w*16 + quad*4 + r) * 296 + m] = ov;
        }
    }
    __syncthreads();

    // coalesced store: 64 rows x 288 u16 (= 36 uint4 chunks per row)
    u16* obase = OutP + ((size_t)bh * NSEQ + n0) * MP;
    for (int i = t; i < 2304; i += 256) {
        int row = i / 36, c = i - row * 36;
        *(uint4*)(obase + row*MP + c*8) = *(const uint4*)(smem16 + row*296 + c*8);
    }
}

__global__ void gmax_reduce(const u32* __restrict__ gpart, u32* __restrict__ gmax)
{
    __shared__ u32 r[256];
    int t = threadIdx.x;
    r[t] = gpart[t]; __syncthreads();
    for (int s = 128; s; s >>= 1) { if (t < s) r[t] = max(r[t], r[t + s]); __syncthreads(); }
    if (t == 0) *gmax = r[0];
}

// ---------------------------------------------------------------------------
// Phase A: per-chunk S^T[d][m] = sum_n V[n][d]*k_true[n][m] via MFMA -> bf16 Sb;
// k_true = s(n)*k_loc + RATIO*KEPS applied during KT transpose staging.
// T5: setprio around the per-quarter MFMA burst.
// ---------------------------------------------------------------------------
__global__ __launch_bounds__(256)
void chunk_ST(const u16* __restrict__ Kp, const u16* __restrict__ Vb,
              u16* __restrict__ Sb, float* __restrict__ zf,
              const float* __restrict__ lstab, const u32* __restrict__ gmax)
{
    int bhc = blockIdx.x;             // 1024
    int bh = bhc >> 5, c = bhc & (NC - 1);
    int b = bh >> 4, h = bh & 15;
    int t = threadIdx.x, w = t >> 6, lane = t & 63;
    int quad = lane >> 4, l16 = lane & 15;
    int n0 = c * CH;

    float gv = dec_max(*gmax);
    float sA = __expf(lstab[bh*64 + c*2] - gv);
    float sB = __expf(lstab[bh*64 + c*2 + 1] - gv);

    __shared__ __align__(16) u16 KTs[288*40];   // 23040 B (quarter: 32 n)
    __shared__ __align__(16) u16 VTs[80*136];   // 21760 B

    // stage VT (transposed V), ones row 64, zero rows 65..79
    {
        int d0 = (t >> 5) * 8, nb = (t & 31) * 4;
        const u16* vb2 = Vb + ((size_t)(b*NSEQ + n0 + nb)) * DM + h*DH + d0;
        uint4 r0 = *(const uint4*)(vb2);
        uint4 r1 = *(const uint4*)(vb2 + DM);
        uint4 r2 = *(const uint4*)(vb2 + 2*DM);
        uint4 r3 = *(const uint4*)(vb2 + 3*DM);
        const u32* a0 = (const u32*)&r0; const u32* a1 = (const u32*)&r1;
        const u32* a2 = (const u32*)&r2; const u32* a3 = (const u32*)&r3;
        #pragma unroll
        for (int e = 0; e < 8; ++e) {
            u32 w0 = a0[e>>1], w1 = a1[e>>1], w2 = a2[e>>1], w3 = a3[e>>1];
            u32 lo2, hi2;
            if (e & 1) { lo2 = (w0 >> 16) | (w1 & 0xFFFF0000u); hi2 = (w2 >> 16) | (w3 & 0xFFFF0000u); }
            else       { lo2 = (w0 & 0xFFFFu) | (w1 << 16);     hi2 = (w2 & 0xFFFFu) | (w3 << 16); }
            uint2 uu; uu.x = lo2; uu.y = hi2;
            *(uint2*)&VTs[(d0 + e)*136 + nb] = uu;
        }
        if (t < 128) VTs[64*136 + t] = 0x3F80u;      // ones row (bf16 1.0)
        if (t < 255) {                                // zero rows 65..79
            int rr = 65 + t/17, cc2 = t - (t/17)*17;
            uint4 z4 = (uint4){0,0,0,0};
            *(uint4*)&VTs[rr*136 + cc2*8] = z4;
        }
    }

    f32x4 am[18], az[5];
    #pragma unroll
    for (int mt = 0; mt < 18; ++mt) am[mt] = (f32x4){0.f,0.f,0.f,0.f};
    #pragma unroll
    for (int j = 0; j < 5; ++j) az[j] = (f32x4){0.f,0.f,0.f,0.f};

    const u16* kbase = Kp + ((size_t)bh * NSEQ + n0) * MP;
    for (int qh = 0; qh < 4; ++qh) {
        float sq4 = (qh < 2) ? sA : sB;
        __syncthreads();
        // stage KT quarter: [288 m][32 n], apply k_true = s*k_loc + RK
        for (int i = t; i < 288; i += 256) {
            int nb4 = (i & 7) * 4, m0 = (i >> 3) * 8;
            const u16* kb = kbase + (size_t)(qh*32 + nb4) * MP + m0;
            uint4 r0 = *(const uint4*)(kb);
            uint4 r1 = *(const uint4*)(kb + MP);
            uint4 r2 = *(const uint4*)(kb + 2*MP);
            uint4 r3 = *(const uint4*)(kb + 3*MP);
            const u32* a0 = (const u32*)&r0; const u32* a1 = (const u32*)&r1;
            const u32* a2 = (const u32*)&r2; const u32* a3 = (const u32*)&r3;
            #pragma unroll
            for (int e = 0; e < 8; ++e) {
                u32 w0 = a0[e>>1], w1 = a1[e>>1], w2 = a2[e>>1], w3 = a3[e>>1];
                u16 e0, e1, e2, e3;
                if (e & 1) { e0 = (u16)(w0 >> 16); e1 = (u16)(w1 >> 16); e2 = (u16)(w2 >> 16); e3 = (u16)(w3 >> 16); }
                else       { e0 = (u16)w0; e1 = (u16)w1; e2 = (u16)w2; e3 = (u16)w3; }
                u16 f0 = f2b(b2f(e0)*sq4 + RKC);
                u16 f1 = f2b(b2f(e1)*sq4 + RKC);
                u16 f2 = f2b(b2f(e2)*sq4 + RKC);
                u16 f3 = f2b(b2f(e3)*sq4 + RKC);
                uint2 uu; uu.x = (u32)f0 | ((u32)f1 << 16); uu.y = (u32)f2 | ((u32)f3 << 16);
                *(uint2*)&KTs[(m0 + e)*40 + nb4] = uu;
            }
        }
        __syncthreads();
        int nof = qh*32 + quad*8;
        bf16x8 aw = *(const bf16x8*)&VTs[(w*16 + l16)*136 + nof];
        bf16x8 a4 = *(const bf16x8*)&VTs[(64 + l16)*136 + nof];
        __builtin_amdgcn_s_setprio(1);
        #pragma unroll
        for (int mt = 0; mt < 18; ++mt) {
            bf16x8 bk = *(const bf16x8*)&KTs[(mt*16 + l16)*40 + quad*8];
            am[mt] = __builtin_amdgcn_mfma_f32_16x16x32_bf16(aw, bk, am[mt], 0, 0, 0);
        }
        #pragma unroll
        for (int j = 0; j < 5; ++j) {
            int mtz = w + 4*j;
            if (mtz < 18) {
                bf16x8 bk = *(const bf16x8*)&KTs[(mtz*16 + l16)*40 + quad*8];
                az[j] = __builtin_amdgcn_mfma_f32_16x16x32_bf16(a4, bk, az[j], 0, 0, 0);
            }
        }
        __builtin_amdgcn_s_setprio(0);
    }

    u16* sb = Sb + (size_t)bhc * SELEM;
    #pragma unroll
    for (int mt = 0; mt < 18; ++mt)
        #pragma unroll
        for (int r = 0; r < 4; ++r)
            sb[(size_t)(w*16 + quad*4 + r) * MP + mt*16 + l16] = f2b(am[mt][r]);
    if (quad == 0) {
        #pragma unroll
        for (int j = 0; j < 5; ++j) {
            int mtz = w + 4*j;
            if (mtz < 18) zf[(size_t)bhc * MP + mtz*16 + l16] = az[j][0];
        }
    }
}

// ---------------------------------------------------------------------------
// Phase B: in-place exclusive prefix over 32 chunks per (b,h), VECTORIZED.
// grid = 297 blocks exactly.
// ---------------------------------------------------------------------------
__global__ __launch_bounds__(256)
void chunk_prefix(u16* __restrict__ Sb, float* __restrict__ zf)
{
    int gid = blockIdx.x * 256 + threadIdx.x;   // < 76032
    if (gid < 32 * (SELEM/8)) {
        int bh = gid / (SELEM/8);
        int e8 = gid - bh * (SELEM/8);
        size_t base = (size_t)(bh * NC) * SELEM + (size_t)e8 * 8;
        float run[8];
        #pragma unroll
        for (int j = 0; j < 8; ++j) run[j] = 0.f;
        for (int c2 = 0; c2 < NC; ++c2) {
            u16* p = Sb + base + (size_t)c2 * SELEM;
            uint4 v = *(uint4*)p;
            u16* e = (u16*)&v;
            #pragma unroll
            for (int j = 0; j < 8; ++j) {
                float x = b2f(e[j]);
                e[j] = f2b(run[j]);
                run[j] += x;
            }
            *(uint4*)p = v;
        }
    } else {
        int g2 = gid - 32 * (SELEM/8);   // < 32*72 = 2304
        int bh = g2 / (MP/4);
        int m4 = g2 - bh * (MP/4);
        size_t base = (size_t)(bh * NC) * MP + (size_t)m4 * 4;
        float run0 = 0.f, run1 = 0.f, run2 = 0.f, run3 = 0.f;
        for (int c2 = 0; c2 < NC; ++c2) {
            float* p = zf + base + (size_t)c2 * MP;
            float4 v = *(float4*)p;
            float t0 = v.x, t1 = v.y, t2 = v.z, t3 = v.w;
            v.x = run0 + CEPS; v.y = run1 + CEPS; v.z = run2 + CEPS; v.w = run3 + CEPS;
            run0 += t0; run1 += t1; run2 += t2; run3 += t3;
            *(float4*)p = v;
        }
    }
}

// ---------------------------------------------------------------------------
// Phase C: MFMA causal chunk attention. Block = one 128-token chunk, 4 waves.
// K-rescale during K LDS staging. T5: setprio around MFMA bursts.
// ---------------------------------------------------------------------------
__global__ __launch_bounds__(256)
void scan_mfma(const u16* __restrict__ Qp, const u16* __restrict__ Kp,
               const u16* __restrict__ Vb, const u16* __restrict__ Sb,
               const float* __restrict__ zf, const float* __restrict__ lstab,
               const u32* __restrict__ gmax, u16* __restrict__ attn)
{
    int bhc = blockIdx.x;             // 1024
    int bh = bhc >> 5, c = bhc & (NC - 1);
    int b = bh >> 4, h = bh & 15;
    int t = threadIdx.x, w = t >> 6, lane = t & 63;
    int quad = lane >> 4, l16 = lane & 15;
    int n0 = c * CH;
    int it0 = w, it1 = 7 - w;

    __shared__ __align__(16) u16 R1s[9472];    // K quarter [32][296] -> VT [64][136] -> S half [32][296]
    __shared__ __align__(16) u16 R2s[17408];   // P [128][136]

    float gv = dec_max(*gmax);
    float sA = __expf(lstab[bh*64 + c*2] - gv);
    float sB = __expf(lstab[bh*64 + c*2 + 1] - gv);

    // zero P region (upper-triangle tiles never written)
    for (int i = t; i < 2176; i += 256) ((uint4*)R2s)[i] = (uint4){0,0,0,0};

    // Q fragments for both i-tiles (reused by QK^T as B and carry as A)
    bf16x8 q0[9], q1[9];
    {
        const u16* qa = Qp + ((size_t)bh * NSEQ + n0 + it0*16 + l16) * MP + quad*8;
        const u16* qb = Qp + ((size_t)bh * NSEQ + n0 + it1*16 + l16) * MP + quad*8;
        #pragma unroll
        for (int s = 0; s < 9; ++s) {
            q0[s] = *(const bf16x8*)(qa + s*32);
            q1[s] = *(const bf16x8*)(qb + s*32);
        }
    }

    float denw0 = 0.f, denw1 = 0.f;
    const u16* kbase = Kp + ((size_t)bh * NSEQ + n0) * MP;

    for (int qt = 0; qt < 4; ++qt) {
        float sq4 = (qt < 2) ? sA : sB;
        __syncthreads();
        // stage K quarter with on-the-fly rescale: k_true = s*k_loc + RK
        for (int i = t; i < 1152; i += 256) {
            int rr = i / 36, cc = i - rr * 36;
            uint4 v = *(const uint4*)(kbase + (size_t)(qt*32 + rr) * MP + cc*8);
            u16* e = (u16*)&v;
            #pragma unroll
            for (int j = 0; j < 8; ++j) e[j] = f2b(b2f(e[j])*sq4 + RKC);
            *(uint4*)&R1s[rr*296 + cc*8] = v;
        }
        __syncthreads();
        #pragma unroll
        for (int jj = 0; jj < 2; ++jj) {
            int jt = qt*2 + jj;
            #pragma unroll
            for (int itx = 0; itx < 2; ++itx) {
                int it = itx ? it1 : it0;
                if (jt <= it) {
                    f32x4 acc = (f32x4){0.f,0.f,0.f,0.f};
                    __builtin_amdgcn_s_setprio(1);
                    #pragma unroll
                    for (int s = 0; s < 9; ++s) {
                        bf16x8 kf = *(const bf16x8*)&R1s[(jj*16 + l16)*296 + s*32 + quad*8];
                        acc = __builtin_amdgcn_mfma_f32_16x16x32_bf16(
                            kf, itx ? q1[s] : q0[s], acc, 0, 0, 0);
                    }
                    __builtin_amdgcn_s_setprio(0);
                    int ig = it*16 + l16;
                    float rs = 0.f;
                    #pragma unroll
                    for (int r = 0; r < 4; ++r) {
                        int jg = jt*16 + quad*4 + r;
                        float pv = (jg <= ig) ? acc[r] : 0.f;
                        rs += pv;
                        R2s[ig*136 + jg] = f2b(pv);
                    }
                    if (itx) denw1 += rs; else denw0 += rs;
                }
            }
        }
    }

    __syncthreads();
    // stage VT (transposed V) into R1 ([64][136])
    {
        int d0 = (t >> 5) * 8, nb = (t & 31) * 4;
        const u16* vb2 = Vb + ((size_t)(b*NSEQ + n0 + nb)) * DM + h*DH + d0;
        uint4 r0 = *(const uint4*)(vb2);
        uint4 r1 = *(const uint4*)(vb2 + DM);
        uint4 r2 = *(const uint4*)(vb2 + 2*DM);
        uint4 r3 = *(const uint4*)(vb2 + 3*DM);
        const u32* a0 = (const u32*)&r0; const u32* a1 = (const u32*)&r1;
        const u32* a2 = (const u32*)&r2; const u32* a3 = (const u32*)&r3;
        #pragma unroll
        for (int e = 0; e < 8; ++e) {
            u32 w0 = a0[e>>1], w1 = a1[e>>1], w2 = a2[e>>1], w3 = a3[e>>1];
            u32 lo2, hi2;
            if (e & 1) { lo2 = (w0 >> 16) | (w1 & 0xFFFF0000u); hi2 = (w2 >> 16) | (w3 & 0xFFFF0000u); }
            else       { lo2 = (w0 & 0xFFFFu) | (w1 << 16);     hi2 = (w2 & 0xFFFFu) | (w3 << 16); }
            uint2 uu; uu.x = lo2; uu.y = hi2;
            *(uint2*)&R1s[(d0 + e)*136 + nb] = uu;
        }
    }
    __syncthreads();

    // PV: out[i][d] += P[i][j] * VT[d][j]
    f32x4 pacc[2][4];
    #pragma unroll
    for (int i = 0; i < 2; ++i)
        #pragma unroll
        for (int j = 0; j < 4; ++j) pacc[i][j] = (f32x4){0.f,0.f,0.f,0.f};
    int ns0 = (it0 + 2) >> 1, ns1 = (it1 + 2) >> 1;
    __builtin_amdgcn_s_setprio(1);
    #pragma unroll
    for (int ks = 0; ks < 4; ++ks) {
        bool u0 = ks < ns0, u1 = ks < ns1;
        bf16x8 p0 = {}, p1 = {};
        if (u0) p0 = *(const bf16x8*)&R2s[(it0*16 + l16)*136 + ks*32 + quad*8];
        if (u1) p1 = *(const bf16x8*)&R2s[(it1*16 + l16)*136 + ks*32 + quad*8];
        #pragma unroll
        for (int ct = 0; ct < 4; ++ct) {
            bf16x8 vf = *(const bf16x8*)&R1s[(ct*16 + l16)*136 + ks*32 + quad*8];
            if (u0) pacc[0][ct] = __builtin_amdgcn_mfma_f32_16x16x32_bf16(p0, vf, pacc[0][ct], 0, 0, 0);
            if (u1) pacc[1][ct] = __builtin_amdgcn_mfma_f32_16x16x32_bf16(p1, vf, pacc[1][ct], 0, 0, 0);
        }
    }
    __builtin_amdgcn_s_setprio(0);

    // carry: out[i][d] += Q[i][m] * S^T[d][m] — bf16, 2 half-staging passes
    f32x4 cacc[2][4];
    #pragma unroll
    for (int i = 0; i < 2; ++i)
        #pragma unroll
        for (int j = 0; j < 4; ++j) cacc[i][j] = (f32x4){0.f,0.f,0.f,0.f};
    const u16* sbw = Sb + (size_t)bhc * SELEM;
    #pragma unroll
    for (int p = 0; p < 2; ++p) {
        __syncthreads();
        for (int i = t; i < 1152; i += 256) {
            int rr = i / 36, cc = i - rr * 36;
            *(uint4*)&R1s[rr*296 + cc*8] =
                *(const uint4*)(sbw + (size_t)(p*32 + rr) * MP + cc*8);
        }
        __syncthreads();
        __builtin_amdgcn_s_setprio(1);
        #pragma unroll
        for (int s = 0; s < 9; ++s)
            #pragma unroll
            for (int cl = 0; cl < 2; ++cl) {
                bf16x8 sf = *(const bf16x8*)&R1s[(cl*16 + l16)*296 + s*32 + quad*8];
                cacc[0][p*2 + cl] = __builtin_amdgcn_mfma_f32_16x16x32_bf16(q0[s], sf, cacc[0][p*2 + cl], 0, 0, 0);
                cacc[1][p*2 + cl] = __builtin_amdgcn_mfma_f32_16x16x32_bf16(q1[s], sf, cacc[1][p*2 + cl], 0, 0, 0);
            }
        __builtin_amdgcn_s_setprio(0);
    }

    // den carry: q . (z_prefix + CEPS), fp32
    float dc0 = 0.f, dc1 = 0.f;
    {
        const float* zc = zf + (size_t)bhc * MP + quad*8;
        #pragma unroll
        for (int s = 0; s < 9; ++s) {
            f32x4 za = *(const f32x4*)(zc + s*32);
            f32x4 zb = *(const f32x4*)(zc + s*32 + 4);
            #pragma unroll
            for (int e = 0; e < 4; ++e) {
                dc0 += (float)q0[s][e] * za[e];
                dc0 += (float)q0[s][e+4] * zb[e];
                dc1 += (float)q1[s][e] * za[e];
                dc1 += (float)q1[s][e+4] * zb[e];
            }
        }
    }
    dc0 += __shfl_xor(dc0, 16, 64); dc0 += __shfl_xor(dc0, 32, 64);
    dc1 += __shfl_xor(dc1, 16, 64); dc1 += __shfl_xor(dc1, 32, 64);
    denw0 += __shfl_xor(denw0, 16, 64); denw0 += __shfl_xor(denw0, 32, 64);
    denw1 += __shfl_xor(denw1, 16, 64); denw1 += __shfl_xor(denw1, 32, 64);
    float den0 = denw0 + dc0, den1 = denw1 + dc1;

    // output
    u16* ab = attn + ((size_t)(b*NSEQ + n0)) * DM + h*DH;
    #pragma unroll
    for (int itx = 0; itx < 2; ++itx) {
        int it = itx ? it1 : it0;
        float dv = itx ? den1 : den0;
        #pragma unroll
        for (int r = 0; r < 4; ++r) {
            float deno = __shfl(dv, (lane & 48) + quad*4 + r, 64);
            int row = it*16 + quad*4 + r;
            #pragma unroll
            for (int ct = 0; ct < 4; ++ct) {
                float ov = (pacc[itx][ct][r] + cacc[itx][ct][r]) / deno;
                ab[(size_t)row * DM + ct*16 + l16] = f2b(ov);
            }
        }
    }
}

// ---------------------------------------------------------------------------
extern "C" void kernel_launch(void* const* d_in, const int* in_sizes, int n_in,
                              void* d_out, int out_size, void* d_ws, size_t ws_size,
                              hipStream_t stream)
{
    (void)n_in; (void)out_size; (void)ws_size;
    const void* x  = d_in[0];
    const void* Wq = d_in[1]; const void* bq = d_in[2];
    const void* Wk = d_in[3]; const void* bk = d_in[4];
    const void* Wv = d_in[5]; const void* bv = d_in[6];
    const void* Wo = d_in[7]; const void* bo = d_in[8];
    const void* proj = d_in[9];

    char* ws = (char*)d_ws;
    size_t off = 0;
    auto alloc = [&](size_t bytes) -> char* {
        char* p = ws + off; off += (bytes + 255) & ~(size_t)255; return p;
    };
    // overlay region: {Qh,Ql,Kh,Kl} (67.1 MB, dead after feat_qk) / {Sb, zf} (38.9 MB)
    size_t plBytes  = (size_t)NROWS * DM * 2;    // one bf16 plane = 16.8 MB
    size_t sbBytes  = (size_t)(B_ * H_ * NC) * SELEM * 2;
    size_t zfBytes  = (size_t)(B_ * H_ * NC) * MP * 4;
    size_t ovBytes  = 4 * plBytes;
    if (sbBytes + zfBytes > ovBytes) ovBytes = sbBytes + zfBytes;
    char*  ov0  = alloc(ovBytes);
    u16*   Qh   = (u16*)ov0;
    u16*   Ql   = (u16*)(ov0 + plBytes);
    u16*   Kh   = (u16*)(ov0 + 2*plBytes);
    u16*   Kl   = (u16*)(ov0 + 3*plBytes);
    u16*   Sb   = (u16*)ov0;
    float* zfp  = (float*)(ov0 + sbBytes);
    u16*   Vb   = (u16*)alloc((size_t)NROWS * DM * 2);
    u16*   Qp   = (u16*)alloc((size_t)NHROWS * MP * 2);
    u16*   Kp   = (u16*)alloc((size_t)NHROWS * MP * 2);
    u16*   projC= (u16*)alloc((size_t)MP * DH * 2);
    u16*   Wqb  = (u16*)alloc((size_t)DM * DM * 2);
    u16*   Wkb  = (u16*)alloc((size_t)DM * DM * 2);
    u16*   Wvb  = (u16*)alloc((size_t)DM * DM * 2);
    u16*   Wob  = (u16*)alloc((size_t)DM * DM * 2);
    u16*   bqb  = (u16*)alloc(DM * 2);
    u16*   bkb  = (u16*)alloc(DM * 2);
    u16*   bvb  = (u16*)alloc(DM * 2);
    u16*   bob  = (u16*)alloc(DM * 2);
    u32*   flags= (u32*)alloc(16 * 4);
    u32*   gmax = (u32*)alloc(256);
    u32*   gpart= (u32*)alloc(256 * 4);
    float* lstab= (float*)alloc(2048 * 4);
    char*  xatt = alloc((size_t)NROWS * DM * 2);
    u16*   xb   = (u16*)xatt;    // alias: xb dead after gemm_qkv
    u16*   attn = (u16*)xatt;    // scan writes afterwards

    DetectArgs da;
    for (int i = 0; i < 10; ++i) {
        int n = in_sizes[i];
        int nwords = n / 2; if (nwords > 4096) nwords = 4096;
        da.p[i] = (const u32*)d_in[i];
        da.nw[i] = nwords;
    }
    detect_all<<<10, 256, 0, stream>>>(da, flags);

    ConvAllArgs ca;
    ca.xs = x;  ca.xd = xb;
    ca.wsrc[0] = Wq; ca.wsrc[1] = Wk; ca.wsrc[2] = Wv; ca.wsrc[3] = Wo;
    ca.wdst[0] = Wqb; ca.wdst[1] = Wkb; ca.wdst[2] = Wvb; ca.wdst[3] = Wob;
    ca.bsrc[0] = bq; ca.bsrc[1] = bk; ca.bsrc[2] = bv; ca.bsrc[3] = bo;
    ca.bdst[0] = bqb; ca.bdst[1] = bkb; ca.bdst[2] = bvb; ca.bdst[3] = bob;
    ca.pj = proj; ca.pjd = projC;
    ca.gpart = gpart; ca.gmax = gmax; ca.flags = flags;
    conv_all<<<6158, 256, 0, stream>>>(ca);

    dim3 gq(NROWS / 128, DM / 128, 3);
    gemm_qkv<<<gq, 256, 0, stream>>>(xb, Wqb, Wkb, Wvb, bqb, bkb, bvb,
                                     Vb, Qh, Ql, Kh, Kl);

    // fused Q-feat + K-feat (hi/lo bf16 planes in); global max via gpart
    feat_qk<<<4096, 256, 0, stream>>>(Qh, Ql, Kh, Kl, projC, Qp, Kp, gpart, lstab);
    gmax_reduce<<<1, 256, 0, stream>>>(gpart, gmax);

    // MFMA chunk-parallel causal scan; K global-rescale folded into staging
    chunk_ST<<<B_ * H_ * NC, 256, 0, stream>>>(Kp, Vb, Sb, zfp, lstab, gmax);
    chunk_prefix<<<297, 256, 0, stream>>>(Sb, zfp);
    scan_mfma<<<B_ * H_ * NC, 256, 0, stream>>>(Qp, Kp, Vb, Sb, zfp, lstab, gmax, attn);

    // OUTPUT IS FP32 (reference's output dtype, per harness instructions).
    gemm_nt<<<512, 256, 0, stream>>>(attn, Wob, bob, (float*)d_out);
}

// Round 17
// 362.055 us; speedup vs baseline: 1.0096x; 1.0096x over previous
//
#include <hip/hip_runtime.h>

#define B_    2
#define NSEQ  4096
#define DM    1024
#define H_    16
#define DH    64
#define MF    266
#define MP    288          // padded feature count, 9 x 32 (pads are zero)
#define NROWS (B_*NSEQ)    // 8192
#define NHROWS (B_*H_*NSEQ) // 131072
#define RATIO 0.06131393394849658f   // 266^-0.5
#define DNORM 0.3535533905932738f    // 64^-0.25
#define KEPS  1e-4f
#define CEPS  1e-6f
#define RKC   (RATIO*KEPS)

// chunked causal scan geometry
#define CH    128                 // tokens per chunk
#define NC    32                  // chunks per (b,h) = NSEQ/CH
#define SROW  (65*MP)             // logical per-chunk state elems (64 S rows + z row)
#define SELEM (64*MP)             // S elems per chunk (bf16)

#define AS1 __attribute__((address_space(1)))
#define AS3 __attribute__((address_space(3)))

typedef unsigned short u16;
typedef unsigned int   u32;

typedef __bf16 bf16x8 __attribute__((ext_vector_type(8)));
typedef float  f32x4  __attribute__((ext_vector_type(4)));

__device__ __forceinline__ float b2f(u16 u){ u32 x = ((u32)u) << 16; return __builtin_bit_cast(float, x); }
__device__ __forceinline__ u16 f2b(float f){
    return __builtin_bit_cast(u16, (__bf16)f);   // native RTNE cvt
}
__device__ __forceinline__ u32 enc_max(float f){ u32 b = __builtin_bit_cast(u32, f); return (b & 0x80000000u) ? ~b : (b | 0x80000000u); }
__device__ __forceinline__ float dec_max(u32 u){ u32 b = (u & 0x80000000u) ? (u & 0x7fffffffu) : ~u; return __builtin_bit_cast(float, b); }

// ---------------------------------------------------------------------------
// Per-input dtype detection, all 10 inputs in one launch. flag 1=bf16, 0=fp32.
// ---------------------------------------------------------------------------
struct DetectArgs { const u32* p[10]; int nw[10]; };

__global__ void detect_all(DetectArgs a, u32* __restrict__ flags)
{
    __shared__ int cnt[256];
    int k = blockIdx.x;
    const u32* src = a.p[k];
    int nwords = a.nw[k];
    int t = threadIdx.x; int c = 0;
    for (int i = t; i < nwords; i += 256) {
        u32 w = src[i];
        int ea = (int)((w >> 7)  & 0xFF);
        int eb = (int)((w >> 23) & 0xFF);
        c += (ea >= 112 && ea <= 143) ? 1 : 0;
        c += (eb >= 112 && eb <= 143) ? 1 : 0;
    }
    cnt[t] = c; __syncthreads();
    for (int s = 128; s; s >>= 1) { if (t < s) cnt[t] += cnt[t + s]; __syncthreads(); }
    if (t == 0) flags[k] = (cnt[0] >= (nwords * 3) / 2) ? 1u : 0u;  // 75% of 2*nwords
}

// ---------------------------------------------------------------------------
// Consolidated conversion: x, Wq/Wk/Wv/Wo, 4 biases, proj (+pad), gpart/gmax 0.
// ---------------------------------------------------------------------------
__device__ __forceinline__ void conv8(const void* src, u16* dst, int i, u32 flag)
{
    if (flag) {
        *(uint4*)(dst + i) = *(const uint4*)((const u16*)src + i);
    } else {
        const float* s = (const float*)src + i;
        u16 tmp[8];
        #pragma unroll
        for (int j = 0; j < 8; ++j) tmp[j] = f2b(s[j]);
        *(uint4*)(dst + i) = *(uint4*)tmp;
    }
}

struct ConvAllArgs {
    const void* xs;    u16* xd;
    const void* wsrc[4]; u16* wdst[4];   // Wq,Wk,Wv,Wo (flags 1,3,5,7)
    const void* bsrc[4]; u16* bdst[4];   // bq,bk,bv,bo (flags 2,4,6,8)
    const void* pj;    u16* pjd;
    u32* gpart; u32* gmax;
    const u32* flags;
};

// grid: 4096 (x) + 2048 (W) + 4 (bias) + 9 (proj) + 1 (misc) = 6158 blocks
__global__ __launch_bounds__(256)
void conv_all(ConvAllArgs a)
{
    int blk = blockIdx.x, t = threadIdx.x;
    if (blk < 4096) {
        int i = blk * 2048 + t * 8;
        conv8(a.xs, a.xd, i, a.flags[0]);
    } else if (blk < 6144) {
        int r = blk - 4096; int w = r >> 9; int i = (r & 511) * 2048 + t * 8;
        conv8(a.wsrc[w], a.wdst[w], i, a.flags[1 + 2*w]);
    } else if (blk < 6148) {
        int w = blk - 6144; int i = t * 8;
        if (i < DM) conv8(a.bsrc[w], a.bdst[w], i, a.flags[2 + 2*w]);
    } else if (blk < 6157) {
        int i = (blk - 6148) * 2048 + t * 8;   // < MP*DH = 18432
        if (i < MF * DH) conv8(a.pj, a.pjd, i, a.flags[9]);
        else             *(uint4*)(a.pjd + i) = (uint4){0,0,0,0};
    } else {
        a.gpart[t] = 0u;
        if (t == 0) *a.gmax = 0u;
    }
}

// ---------------------------------------------------------------------------
// GEMM body (m97 structure, BK=64): C[r][c] = sum_k A[r][k]*W[c][k].
// ---------------------------------------------------------------------------
#define GEMM_BODY(A_, Bm_, bm_, bn_, ACC_)                                    \
    const int K = DM;                                                          \
    __shared__ u16 As[128 * 64];                                               \
    __shared__ u16 Bs[128 * 64];                                               \
    int t = threadIdx.x;                                                       \
    int wave = t >> 6, lane = t & 63;                                          \
    int wm = wave >> 1, wn = wave & 1;                                         \
    int quad = lane >> 4, l16 = lane & 15;                                     \
    int rowc = lane >> 3;                                                      \
    int csrc = ((lane & 7) ^ rowc) * 8;                                        \
    int cA = wave * 4;                                                         \
    const u16* ap0 = A_  + (size_t)(bm_ + cA*8 + rowc) * K + csrc;             \
    const u16* bp0 = Bm_ + (size_t)(bn_ + cA*8 + rowc) * K + csrc;             \
    u16* lA = As + cA * 512;                                                   \
    u16* lB = Bs + cA * 512;                                                   \
    f32x4 ACC_[4][4];                                                          \
    _Pragma("unroll")                                                          \
    for (int i = 0; i < 4; ++i)                                                \
        _Pragma("unroll")                                                      \
        for (int j = 0; j < 4; ++j) ACC_[i][j] = (f32x4){0.f,0.f,0.f,0.f};     \
    for (int k0 = 0; k0 < K; k0 += 64) {                                       \
        _Pragma("unroll")                                                      \
        for (int j = 0; j < 4; ++j) {                                          \
            __builtin_amdgcn_global_load_lds((const AS1 void*)(ap0 + (size_t)j*8*K + k0), (AS3 void*)(lA + j*512), 16, 0, 0); \
            __builtin_amdgcn_global_load_lds((const AS1 void*)(bp0 + (size_t)j*8*K + k0), (AS3 void*)(lB + j*512), 16, 0, 0); \
        }                                                                      \
        __syncthreads();                                                       \
        _Pragma("unroll")                                                      \
        for (int ks = 0; ks < 2; ++ks) {                                       \
            bf16x8 af[4], bfr[4];                                              \
            int sw = ((((ks << 2) | quad) ^ (l16 & 7)) << 4);                  \
            _Pragma("unroll")                                                  \
            for (int i = 0; i < 4; ++i) {                                      \
                af[i]  = *(const bf16x8*)((const char*)As + (wm*64 + i*16 + l16)*128 + sw); \
                bfr[i] = *(const bf16x8*)((const char*)Bs + (wn*64 + i*16 + l16)*128 + sw); \
            }                                                                  \
            _Pragma("unroll")                                                  \
            for (int i = 0; i < 4; ++i)                                        \
                _Pragma("unroll")                                              \
                for (int j = 0; j < 4; ++j)                                    \
                    ACC_[i][j] = __builtin_amdgcn_mfma_f32_16x16x32_bf16(af[i], bfr[j], ACC_[i][j], 0, 0, 0); \
        }                                                                      \
        __syncthreads();                                                       \
    }

// QKV fused: 3D grid (64, 8, 3). z=0 -> V (bf16). z=1/2 -> Q/K written as
// DNORM-scaled hi/lo bf16 planes (the exact decomposition feat_qk needs):
// v = (acc+bias)*DNORM; hi=bf16(v); lo=bf16(v-hi). Saves the fp32 round-trip.
__global__ __launch_bounds__(256)
void gemm_qkv(const u16* __restrict__ A,
              const u16* __restrict__ Wqb, const u16* __restrict__ Wkb,
              const u16* __restrict__ Wvb,
              const u16* __restrict__ bqb, const u16* __restrict__ bkb,
              const u16* __restrict__ bvb,
              u16* __restrict__ Vb,
              u16* __restrict__ Qh, u16* __restrict__ Ql,
              u16* __restrict__ Kh, u16* __restrict__ Kl)
{
    int z  = blockIdx.z;
    int bm = blockIdx.x * 128, bn = blockIdx.y * 128;

    const u16* Bm   = (z == 0) ? Wvb : (z == 1) ? Wqb : Wkb;
    const u16* bias = (z == 0) ? bvb : (z == 1) ? bqb : bkb;
    GEMM_BODY(A, Bm, bm, bn, acc)
    u16* Oh = (z == 1) ? Qh : Kh;
    u16* Ol = (z == 1) ? Ql : Kl;
    #pragma unroll
    for (int i = 0; i < 4; ++i) {
        #pragma unroll
        for (int j = 0; j < 4; ++j) {
            int col = bn + wn*64 + j*16 + l16;
            float bv = b2f(bias[col]);
            #pragma unroll
            for (int r = 0; r < 4; ++r) {
                int row = bm + wm*64 + i*16 + quad*4 + r;
                float v = acc[i][j][r] + bv;
                if (z == 0) {
                    Vb[(size_t)row * DM + col] = f2b(v);
                } else {
                    float vn = v * DNORM;
                    u16 hb = f2b(vn);
                    u16 lb = f2b(vn - b2f(hb));
                    Oh[(size_t)row * DM + col] = hb;
                    Ol[(size_t)row * DM + col] = lb;
                }
            }
        }
    }
}

// out-projection (fp32 output), 1D grid 512, XCD-bijective + 4x4 supergroup
__global__ __launch_bounds__(256)
void gemm_nt(const u16* __restrict__ A, const u16* __restrict__ Bm,
             const u16* __restrict__ bias, float* __restrict__ C)
{
    int bid = blockIdx.x;                 // 0..511
    int xcd = bid & 7, pos = bid >> 3;
    int q   = xcd * 64 + pos;             // contiguous logical range per XCD
    int idx = q & 15, sg = q >> 4;        // 32 supergroups of 4x4
    int sgm = sg & 15, sgn = sg >> 4;     // 16 m-supers, 2 n-supers
    int bm = (sgm*4 + (idx & 3)) * 128;
    int bn = (sgn*4 + (idx >> 2)) * 128;
    GEMM_BODY(A, Bm, bm, bn, acc)
    #pragma unroll
    for (int i = 0; i < 4; ++i) {
        #pragma unroll
        for (int j = 0; j < 4; ++j) {
            int col = bn + wn*64 + j*16 + l16;
            float bv = b2f(bias[col]);
            #pragma unroll
            for (int r = 0; r < 4; ++r) {
                int row = bm + wm*64 + i*16 + quad*4 + r;
                C[(size_t)row * DM + col] = acc[i][j][r] + bv;
            }
        }
    }
}

// ---------------------------------------------------------------------------
// Fused MFMA feature map, Q and K in one launch (grid 4096).
// Inputs are pre-split DNORM-scaled hi/lo bf16 planes (from gemm_qkv).
// blk < 2048: Q rows (per-row stab, +KEPS, write Qp).
// blk >= 2048: K rows — block-local stab l, lstab/gpart; consumers rescale.
// ---------------------------------------------------------------------------
__global__ __launch_bounds__(256)
void feat_qk(const u16* __restrict__ Qhp, const u16* __restrict__ Qlp,
             const u16* __restrict__ Khp, const u16* __restrict__ Klp,
             const u16* __restrict__ projP, u16* __restrict__ Qp,
             u16* __restrict__ Kp, u32* __restrict__ gpart,
             float* __restrict__ lstab)
{
    int blk = blockIdx.x;             // 0..4095
    int isK = blk >> 11;
    int blk2 = blk & 2047;
    int bh = blk2 >> 6, nt = blk2 & 63;
    int b = bh >> 4, h = bh & 15;
    int n0 = nt * 64;
    int t = threadIdx.x;
    int lane = t & 63, w = t >> 6;
    int quad = lane >> 4, l16 = lane & 15;

    const u16* Xh = isK ? Khp : Qhp;
    const u16* Xl = isK ? Klp : Qlp;
    u16* OutP = isK ? Kp : Qp;

    __shared__ uint4 smemU[2368];     // max(proj 288*128B, out 64*296*2B) = 37888B
    __shared__ float red4[4];
    u16* smem16 = (u16*)smemU;

    size_t rbase = ((size_t)(b * NSEQ + n0 + w*16 + l16)) * DM + h * DH;
    bf16x8 ahi[2], alo[2];
    float sq = 0.f;
    #pragma unroll
    for (int ks = 0; ks < 2; ++ks) {
        uint4 hv = *(const uint4*)(Xh + rbase + ks*32 + quad*8);
        uint4 lv = *(const uint4*)(Xl + rbase + ks*32 + quad*8);
        ahi[ks] = __builtin_bit_cast(bf16x8, hv);
        alo[ks] = __builtin_bit_cast(bf16x8, lv);
        const u16* he = (const u16*)&hv;
        const u16* le = (const u16*)&lv;
        #pragma unroll
        for (int i = 0; i < 8; ++i) {
            float v = b2f(he[i]) + b2f(le[i]);
            sq += v * v;
        }
    }
    sq += __shfl_xor(sq, 16, 64);
    sq += __shfl_xor(sq, 32, 64);
    float diag_my = 0.5f * sq;

    // stage proj into LDS, XOR-swizzled: row m at byte m*128, byte^((m&7)<<4)
    for (int i = t; i < 2304; i += 256) {
        int m = i >> 3, c = i & 7;
        uint4 v = *(const uint4*)(projP + m*64 + c*8);
        int dstb = m*128 + ((c*16) ^ ((m & 7) << 4));
        *(uint4*)((char*)smemU + dstb) = v;
    }

    __syncthreads();                  // projS ready

    f32x4 acc[18];
    #pragma unroll
    for (int j = 0; j < 18; ++j) acc[j] = (f32x4){0.f,0.f,0.f,0.f};
    #pragma unroll
    for (int j = 0; j < 18; ++j) {
        int m = j*16 + l16;
        #pragma unroll
        for (int ks = 0; ks < 2; ++ks) {
            int off = m*128 + (((quad*16) + ks*64) ^ ((m & 7) << 4));
            bf16x8 bf = *(const bf16x8*)((const char*)smemU + off);
            acc[j] = __builtin_amdgcn_mfma_f32_16x16x32_bf16(ahi[ks], bf, acc[j], 0, 0, 0);
            acc[j] = __builtin_amdgcn_mfma_f32_16x16x32_bf16(alo[ks], bf, acc[j], 0, 0, 0);
        }
    }

    // per-row max over valid m: tiles 0..15 full; tile 16: l16<10; tile 17: pad
    float rmax[4];
    #pragma unroll
    for (int r = 0; r < 4; ++r) rmax[r] = -3.4e38f;
    #pragma unroll
    for (int j = 0; j < 16; ++j)
        #pragma unroll
        for (int r = 0; r < 4; ++r) rmax[r] = fmaxf(rmax[r], acc[j][r]);
    if (l16 < MF - 256) {
        #pragma unroll
        for (int r = 0; r < 4; ++r) rmax[r] = fmaxf(rmax[r], acc[16][r]);
    }
    #pragma unroll
    for (int s = 1; s < 16; s <<= 1)
        #pragma unroll
        for (int r = 0; r < 4; ++r)
            rmax[r] = fmaxf(rmax[r], __shfl_xor(rmax[r], s, 64));

    float stab_blk = 0.f;
    if (isK) {
        float wm2 = fmaxf(fmaxf(rmax[0], rmax[1]), fmaxf(rmax[2], rmax[3]));
        wm2 = fmaxf(wm2, __shfl_xor(wm2, 16, 64));
        wm2 = fmaxf(wm2, __shfl_xor(wm2, 32, 64));
        if (lane == 0) red4[w] = wm2;
        __syncthreads();
        stab_blk = fmaxf(fmaxf(red4[0], red4[1]), fmaxf(red4[2], red4[3]));
        if (t == 0) {
            atomicMax(&gpart[blk2 & 255], enc_max(stab_blk));
            lstab[blk2] = stab_blk;
        }
    }

    float dg[4];
    #pragma unroll
    for (int r = 0; r < 4; ++r) dg[r] = __shfl(diag_my, quad*4 + r, 64);

    __syncthreads();                  // all proj reads done; reuse LDS as outS

    #pragma unroll
    for (int j = 0; j < 18; ++j) {
        int m = j*16 + l16;
        #pragma unroll
        for (int r = 0; r < 4; ++r) {
            float stab = isK ? stab_blk : rmax[r];
            float ex = __expf(acc[j][r] - dg[r] - stab);
            float val = isK ? (RATIO * ex) : (RATIO * (ex + KEPS));
            u16 ov = (m < MF) ? f2b(val) : (u16)0;
            smem16[(w*16 + quad*4 + r) * 296 + m] = ov;
        }
    }
    __syncthreads();

    // coalesced store: 64 rows x 288 u16 (= 36 uint4 chunks per row)
    u16* obase = OutP + ((size_t)bh * NSEQ + n0) * MP;
    for (int i = t; i < 2304; i += 256) {
        int row = i / 36, c = i - row * 36;
        *(uint4*)(obase + row*MP + c*8) = *(const uint4*)(smem16 + row*296 + c*8);
    }
}

__global__ void gmax_reduce(const u32* __restrict__ gpart, u32* __restrict__ gmax)
{
    __shared__ u32 r[256];
    int t = threadIdx.x;
    r[t] = gpart[t]; __syncthreads();
    for (int s = 128; s; s >>= 1) { if (t < s) r[t] = max(r[t], r[t + s]); __syncthreads(); }
    if (t == 0) *gmax = r[0];
}

// ---------------------------------------------------------------------------
// Phase A: per-chunk S^T[d][m] = sum_n V[n][d]*k_true[n][m] via MFMA -> bf16 Sb;
// k_true = s(n)*k_loc + RATIO*KEPS applied during KT transpose staging.
// VT row 64 = ones -> z (fp32).
// ---------------------------------------------------------------------------
__global__ __launch_bounds__(256)
void chunk_ST(const u16* __restrict__ Kp, const u16* __restrict__ Vb,
              u16* __restrict__ Sb, float* __restrict__ zf,
              const float* __restrict__ lstab, const u32* __restrict__ gmax)
{
    int bhc = blockIdx.x;             // 1024
    int bh = bhc >> 5, c = bhc & (NC - 1);
    int b = bh >> 4, h = bh & 15;
    int t = threadIdx.x, w = t >> 6, lane = t & 63;
    int quad = lane >> 4, l16 = lane & 15;
    int n0 = c * CH;

    float gv = dec_max(*gmax);
    float sA = __expf(lstab[bh*64 + c*2] - gv);
    float sB = __expf(lstab[bh*64 + c*2 + 1] - gv);

    __shared__ __align__(16) u16 KTs[288*40];   // 23040 B (quarter: 32 n)
    __shared__ __align__(16) u16 VTs[80*136];   // 21760 B

    // stage VT (transposed V), ones row 64, zero rows 65..79
    {
        int d0 = (t >> 5) * 8, nb = (t & 31) * 4;
        const u16* vb2 = Vb + ((size_t)(b*NSEQ + n0 + nb)) * DM + h*DH + d0;
        uint4 r0 = *(const uint4*)(vb2);
        uint4 r1 = *(const uint4*)(vb2 + DM);
        uint4 r2 = *(const uint4*)(vb2 + 2*DM);
        uint4 r3 = *(const uint4*)(vb2 + 3*DM);
        const u32* a0 = (const u32*)&r0; const u32* a1 = (const u32*)&r1;
        const u32* a2 = (const u32*)&r2; const u32* a3 = (const u32*)&r3;
        #pragma unroll
        for (int e = 0; e < 8; ++e) {
            u32 w0 = a0[e>>1], w1 = a1[e>>1], w2 = a2[e>>1], w3 = a3[e>>1];
            u32 lo2, hi2;
            if (e & 1) { lo2 = (w0 >> 16) | (w1 & 0xFFFF0000u); hi2 = (w2 >> 16) | (w3 & 0xFFFF0000u); }
            else       { lo2 = (w0 & 0xFFFFu) | (w1 << 16);     hi2 = (w2 & 0xFFFFu) | (w3 << 16); }
            uint2 uu; uu.x = lo2; uu.y = hi2;
            *(uint2*)&VTs[(d0 + e)*136 + nb] = uu;
        }
        if (t < 128) VTs[64*136 + t] = 0x3F80u;      // ones row (bf16 1.0)
        if (t < 255) {                                // zero rows 65..79
            int rr = 65 + t/17, cc2 = t - (t/17)*17;
            uint4 z4 = (uint4){0,0,0,0};
            *(uint4*)&VTs[rr*136 + cc2*8] = z4;
        }
    }

    f32x4 am[18], az[5];
    #pragma unroll
    for (int mt = 0; mt < 18; ++mt) am[mt] = (f32x4){0.f,0.f,0.f,0.f};
    #pragma unroll
    for (int j = 0; j < 5; ++j) az[j] = (f32x4){0.f,0.f,0.f,0.f};

    const u16* kbase = Kp + ((size_t)bh * NSEQ + n0) * MP;
    for (int qh = 0; qh < 4; ++qh) {
        float sq4 = (qh < 2) ? sA : sB;
        __syncthreads();
        // stage KT quarter: [288 m][32 n], apply k_true = s*k_loc + RK
        for (int i = t; i < 288; i += 256) {
            int nb4 = (i & 7) * 4, m0 = (i >> 3) * 8;
            const u16* kb = kbase + (size_t)(qh*32 + nb4) * MP + m0;
            uint4 r0 = *(const uint4*)(kb);
            uint4 r1 = *(const uint4*)(kb + MP);
            uint4 r2 = *(const uint4*)(kb + 2*MP);
            uint4 r3 = *(const uint4*)(kb + 3*MP);
            const u32* a0 = (const u32*)&r0; const u32* a1 = (const u32*)&r1;
            const u32* a2 = (const u32*)&r2; const u32* a3 = (const u32*)&r3;
            #pragma unroll
            for (int e = 0; e < 8; ++e) {
                u32 w0 = a0[e>>1], w1 = a1[e>>1], w2 = a2[e>>1], w3 = a3[e>>1];
                u16 e0, e1, e2, e3;
                if (e & 1) { e0 = (u16)(w0 >> 16); e1 = (u16)(w1 >> 16); e2 = (u16)(w2 >> 16); e3 = (u16)(w3 >> 16); }
                else       { e0 = (u16)w0; e1 = (u16)w1; e2 = (u16)w2; e3 = (u16)w3; }
                u16 f0 = f2b(b2f(e0)*sq4 + RKC);
                u16 f1 = f2b(b2f(e1)*sq4 + RKC);
                u16 f2 = f2b(b2f(e2)*sq4 + RKC);
                u16 f3 = f2b(b2f(e3)*sq4 + RKC);
                uint2 uu; uu.x = (u32)f0 | ((u32)f1 << 16); uu.y = (u32)f2 | ((u32)f3 << 16);
                *(uint2*)&KTs[(m0 + e)*40 + nb4] = uu;
            }
        }
        __syncthreads();
        int nof = qh*32 + quad*8;
        bf16x8 aw = *(const bf16x8*)&VTs[(w*16 + l16)*136 + nof];
        bf16x8 a4 = *(const bf16x8*)&VTs[(64 + l16)*136 + nof];
        #pragma unroll
        for (int mt = 0; mt < 18; ++mt) {
            bf16x8 bk = *(const bf16x8*)&KTs[(mt*16 + l16)*40 + quad*8];
            am[mt] = __builtin_amdgcn_mfma_f32_16x16x32_bf16(aw, bk, am[mt], 0, 0, 0);
        }
        #pragma unroll
        for (int j = 0; j < 5; ++j) {
            int mtz = w + 4*j;
            if (mtz < 18) {
                bf16x8 bk = *(const bf16x8*)&KTs[(mtz*16 + l16)*40 + quad*8];
                az[j] = __builtin_amdgcn_mfma_f32_16x16x32_bf16(a4, bk, az[j], 0, 0, 0);
            }
        }
    }

    u16* sb = Sb + (size_t)bhc * SELEM;
    #pragma unroll
    for (int mt = 0; mt < 18; ++mt)
        #pragma unroll
        for (int r = 0; r < 4; ++r)
            sb[(size_t)(w*16 + quad*4 + r) * MP + mt*16 + l16] = f2b(am[mt][r]);
    if (quad == 0) {
        #pragma unroll
        for (int j = 0; j < 5; ++j) {
            int mtz = w + 4*j;
            if (mtz < 18) zf[(size_t)bhc * MP + mtz*16 + l16] = az[j][0];
        }
    }
}

// ---------------------------------------------------------------------------
// Phase B: in-place exclusive prefix over 32 chunks per (b,h), VECTORIZED.
// grid = 297 blocks exactly.
// ---------------------------------------------------------------------------
__global__ __launch_bounds__(256)
void chunk_prefix(u16* __restrict__ Sb, float* __restrict__ zf)
{
    int gid = blockIdx.x * 256 + threadIdx.x;   // < 76032
    if (gid < 32 * (SELEM/8)) {
        int bh = gid / (SELEM/8);
        int e8 = gid - bh * (SELEM/8);
        size_t base = (size_t)(bh * NC) * SELEM + (size_t)e8 * 8;
        float run[8];
        #pragma unroll
        for (int j = 0; j < 8; ++j) run[j] = 0.f;
        for (int c2 = 0; c2 < NC; ++c2) {
            u16* p = Sb + base + (size_t)c2 * SELEM;
            uint4 v = *(uint4*)p;
            u16* e = (u16*)&v;
            #pragma unroll
            for (int j = 0; j < 8; ++j) {
                float x = b2f(e[j]);
                e[j] = f2b(run[j]);
                run[j] += x;
            }
            *(uint4*)p = v;
        }
    } else {
        int g2 = gid - 32 * (SELEM/8);   // < 32*72 = 2304
        int bh = g2 / (MP/4);
        int m4 = g2 - bh * (MP/4);
        size_t base = (size_t)(bh * NC) * MP + (size_t)m4 * 4;
        float run0 = 0.f, run1 = 0.f, run2 = 0.f, run3 = 0.f;
        for (int c2 = 0; c2 < NC; ++c2) {
            float* p = zf + base + (size_t)c2 * MP;
            float4 v = *(float4*)p;
            float t0 = v.x, t1 = v.y, t2 = v.z, t3 = v.w;
            v.x = run0 + CEPS; v.y = run1 + CEPS; v.z = run2 + CEPS; v.w = run3 + CEPS;
            run0 += t0; run1 += t1; run2 += t2; run3 += t3;
            *(float4*)p = v;
        }
    }
}

// ---------------------------------------------------------------------------
// Phase C: MFMA causal chunk attention. Block = one 128-token chunk, 4 waves.
// K-rescale (k_true = s*k_loc + RK) applied during K LDS staging.
// ---------------------------------------------------------------------------
__global__ __launch_bounds__(256)
void scan_mfma(const u16* __restrict__ Qp, const u16* __restrict__ Kp,
               const u16* __restrict__ Vb, const u16* __restrict__ Sb,
               const float* __restrict__ zf, const float* __restrict__ lstab,
               const u32* __restrict__ gmax, u16* __restrict__ attn)
{
    int bhc = blockIdx.x;             // 1024
    int bh = bhc >> 5, c = bhc & (NC - 1);
    int b = bh >> 4, h = bh & 15;
    int t = threadIdx.x, w = t >> 6, lane = t & 63;
    int quad = lane >> 4, l16 = lane & 15;
    int n0 = c * CH;
    int it0 = w, it1 = 7 - w;

    __shared__ __align__(16) u16 R1s[9472];    // K quarter [32][296] -> VT [64][136] -> S half [32][296]
    __shared__ __align__(16) u16 R2s[17408];   // P [128][136]

    float gv = dec_max(*gmax);
    float sA = __expf(lstab[bh*64 + c*2] - gv);
    float sB = __expf(lstab[bh*64 + c*2 + 1] - gv);

    // zero P region (upper-triangle tiles never written)
    for (int i = t; i < 2176; i += 256) ((uint4*)R2s)[i] = (uint4){0,0,0,0};

    // Q fragments for both i-tiles (reused by QK^T as B and carry as A)
    bf16x8 q0[9], q1[9];
    {
        const u16* qa = Qp + ((size_t)bh * NSEQ + n0 + it0*16 + l16) * MP + quad*8;
        const u16* qb = Qp + ((size_t)bh * NSEQ + n0 + it1*16 + l16) * MP + quad*8;
        #pragma unroll
        for (int s = 0; s < 9; ++s) {
            q0[s] = *(const bf16x8*)(qa + s*32);
            q1[s] = *(const bf16x8*)(qb + s*32);
        }
    }

    float denw0 = 0.f, denw1 = 0.f;
    const u16* kbase = Kp + ((size_t)bh * NSEQ + n0) * MP;

    for (int qt = 0; qt < 4; ++qt) {
        float sq4 = (qt < 2) ? sA : sB;
        __syncthreads();
        // stage K quarter with on-the-fly rescale: k_true = s*k_loc + RK
        for (int i = t; i < 1152; i += 256) {
            int rr = i / 36, cc = i - rr * 36;
            uint4 v = *(const uint4*)(kbase + (size_t)(qt*32 + rr) * MP + cc*8);
            u16* e = (u16*)&v;
            #pragma unroll
            for (int j = 0; j < 8; ++j) e[j] = f2b(b2f(e[j])*sq4 + RKC);
            *(uint4*)&R1s[rr*296 + cc*8] = v;
        }
        __syncthreads();
        #pragma unroll
        for (int jj = 0; jj < 2; ++jj) {
            int jt = qt*2 + jj;
            #pragma unroll
            for (int itx = 0; itx < 2; ++itx) {
                int it = itx ? it1 : it0;
                if (jt <= it) {
                    f32x4 acc = (f32x4){0.f,0.f,0.f,0.f};
                    #pragma unroll
                    for (int s = 0; s < 9; ++s) {
                        bf16x8 kf = *(const bf16x8*)&R1s[(jj*16 + l16)*296 + s*32 + quad*8];
                        acc = __builtin_amdgcn_mfma_f32_16x16x32_bf16(
                            kf, itx ? q1[s] : q0[s], acc, 0, 0, 0);
                    }
                    int ig = it*16 + l16;
                    float rs = 0.f;
                    #pragma unroll
                    for (int r = 0; r < 4; ++r) {
                        int jg = jt*16 + quad*4 + r;
                        float pv = (jg <= ig) ? acc[r] : 0.f;
                        rs += pv;
                        R2s[ig*136 + jg] = f2b(pv);
                    }
                    if (itx) denw1 += rs; else denw0 += rs;
                }
            }
        }
    }

    __syncthreads();
    // stage VT (transposed V) into R1 ([64][136])
    {
        int d0 = (t >> 5) * 8, nb = (t & 31) * 4;
        const u16* vb2 = Vb + ((size_t)(b*NSEQ + n0 + nb)) * DM + h*DH + d0;
        uint4 r0 = *(const uint4*)(vb2);
        uint4 r1 = *(const uint4*)(vb2 + DM);
        uint4 r2 = *(const uint4*)(vb2 + 2*DM);
        uint4 r3 = *(const uint4*)(vb2 + 3*DM);
        const u32* a0 = (const u32*)&r0; const u32* a1 = (const u32*)&r1;
        const u32* a2 = (const u32*)&r2; const u32* a3 = (const u32*)&r3;
        #pragma unroll
        for (int e = 0; e < 8; ++e) {
            u32 w0 = a0[e>>1], w1 = a1[e>>1], w2 = a2[e>>1], w3 = a3[e>>1];
            u32 lo2, hi2;
            if (e & 1) { lo2 = (w0 >> 16) | (w1 & 0xFFFF0000u); hi2 = (w2 >> 16) | (w3 & 0xFFFF0000u); }
            else       { lo2 = (w0 & 0xFFFFu) | (w1 << 16);     hi2 = (w2 & 0xFFFFu) | (w3 << 16); }
            uint2 uu; uu.x = lo2; uu.y = hi2;
            *(uint2*)&R1s[(d0 + e)*136 + nb] = uu;
        }
    }
    __syncthreads();

    // PV: out[i][d] += P[i][j] * VT[d][j]
    f32x4 pacc[2][4];
    #pragma unroll
    for (int i = 0; i < 2; ++i)
        #pragma unroll
        for (int j = 0; j < 4; ++j) pacc[i][j] = (f32x4){0.f,0.f,0.f,0.f};
    int ns0 = (it0 + 2) >> 1, ns1 = (it1 + 2) >> 1;
    #pragma unroll
    for (int ks = 0; ks < 4; ++ks) {
        bool u0 = ks < ns0, u1 = ks < ns1;
        bf16x8 p0 = {}, p1 = {};
        if (u0) p0 = *(const bf16x8*)&R2s[(it0*16 + l16)*136 + ks*32 + quad*8];
        if (u1) p1 = *(const bf16x8*)&R2s[(it1*16 + l16)*136 + ks*32 + quad*8];
        #pragma unroll
        for (int ct = 0; ct < 4; ++ct) {
            bf16x8 vf = *(const bf16x8*)&R1s[(ct*16 + l16)*136 + ks*32 + quad*8];
            if (u0) pacc[0][ct] = __builtin_amdgcn_mfma_f32_16x16x32_bf16(p0, vf, pacc[0][ct], 0, 0, 0);
            if (u1) pacc[1][ct] = __builtin_amdgcn_mfma_f32_16x16x32_bf16(p1, vf, pacc[1][ct], 0, 0, 0);
        }
    }

    // carry: out[i][d] += Q[i][m] * S^T[d][m] — bf16, 2 half-staging passes
    f32x4 cacc[2][4];
    #pragma unroll
    for (int i = 0; i < 2; ++i)
        #pragma unroll
        for (int j = 0; j < 4; ++j) cacc[i][j] = (f32x4){0.f,0.f,0.f,0.f};
    const u16* sbw = Sb + (size_t)bhc * SELEM;
    #pragma unroll
    for (int p = 0; p < 2; ++p) {
        __syncthreads();
        for (int i = t; i < 1152; i += 256) {
            int rr = i / 36, cc = i - rr * 36;
            *(uint4*)&R1s[rr*296 + cc*8] =
                *(const uint4*)(sbw + (size_t)(p*32 + rr) * MP + cc*8);
        }
        __syncthreads();
        #pragma unroll
        for (int s = 0; s < 9; ++s)
            #pragma unroll
            for (int cl = 0; cl < 2; ++cl) {
                bf16x8 sf = *(const bf16x8*)&R1s[(cl*16 + l16)*296 + s*32 + quad*8];
                cacc[0][p*2 + cl] = __builtin_amdgcn_mfma_f32_16x16x32_bf16(q0[s], sf, cacc[0][p*2 + cl], 0, 0, 0);
                cacc[1][p*2 + cl] = __builtin_amdgcn_mfma_f32_16x16x32_bf16(q1[s], sf, cacc[1][p*2 + cl], 0, 0, 0);
            }
    }

    // den carry: q . (z_prefix + CEPS), fp32
    float dc0 = 0.f, dc1 = 0.f;
    {
        const float* zc = zf + (size_t)bhc * MP + quad*8;
        #pragma unroll
        for (int s = 0; s < 9; ++s) {
            f32x4 za = *(const f32x4*)(zc + s*32);
            f32x4 zb = *(const f32x4*)(zc + s*32 + 4);
            #pragma unroll
            for (int e = 0; e < 4; ++e) {
                dc0 += (float)q0[s][e] * za[e];
                dc0 += (float)q0[s][e+4] * zb[e];
                dc1 += (float)q1[s][e] * za[e];
                dc1 += (float)q1[s][e+4] * zb[e];
            }
        }
    }
    dc0 += __shfl_xor(dc0, 16, 64); dc0 += __shfl_xor(dc0, 32, 64);
    dc1 += __shfl_xor(dc1, 16, 64); dc1 += __shfl_xor(dc1, 32, 64);
    denw0 += __shfl_xor(denw0, 16, 64); denw0 += __shfl_xor(denw0, 32, 64);
    denw1 += __shfl_xor(denw1, 16, 64); denw1 += __shfl_xor(denw1, 32, 64);
    float den0 = denw0 + dc0, den1 = denw1 + dc1;

    // output
    u16* ab = attn + ((size_t)(b*NSEQ + n0)) * DM + h*DH;
    #pragma unroll
    for (int itx = 0; itx < 2; ++itx) {
        int it = itx ? it1 : it0;
        float dv = itx ? den1 : den0;
        #pragma unroll
        for (int r = 0; r < 4; ++r) {
            float deno = __shfl(dv, (lane & 48) + quad*4 + r, 64);
            int row = it*16 + quad*4 + r;
            #pragma unroll
            for (int ct = 0; ct < 4; ++ct) {
                float ov = (pacc[itx][ct][r] + cacc[itx][ct][r]) / deno;
                ab[(size_t)row * DM + ct*16 + l16] = f2b(ov);
            }
        }
    }
}

// ---------------------------------------------------------------------------
extern "C" void kernel_launch(void* const* d_in, const int* in_sizes, int n_in,
                              void* d_out, int out_size, void* d_ws, size_t ws_size,
                              hipStream_t stream)
{
    (void)n_in; (void)out_size; (void)ws_size;
    const void* x  = d_in[0];
    const void* Wq = d_in[1]; const void* bq = d_in[2];
    const void* Wk = d_in[3]; const void* bk = d_in[4];
    const void* Wv = d_in[5]; const void* bv = d_in[6];
    const void* Wo = d_in[7]; const void* bo = d_in[8];
    const void* proj = d_in[9];

    char* ws = (char*)d_ws;
    size_t off = 0;
    auto alloc = [&](size_t bytes) -> char* {
        char* p = ws + off; off += (bytes + 255) & ~(size_t)255; return p;
    };
    // overlay region: {Qh,Ql,Kh,Kl} (67.1 MB, dead after feat_qk) / {Sb, zf} (38.9 MB)
    size_t plBytes  = (size_t)NROWS * DM * 2;    // one bf16 plane = 16.8 MB
    size_t sbBytes  = (size_t)(B_ * H_ * NC) * SELEM * 2;
    size_t zfBytes  = (size_t)(B_ * H_ * NC) * MP * 4;
    size_t ovBytes  = 4 * plBytes;
    if (sbBytes + zfBytes > ovBytes) ovBytes = sbBytes + zfBytes;
    char*  ov0  = alloc(ovBytes);
    u16*   Qh   = (u16*)ov0;
    u16*   Ql   = (u16*)(ov0 + plBytes);
    u16*   Kh   = (u16*)(ov0 + 2*plBytes);
    u16*   Kl   = (u16*)(ov0 + 3*plBytes);
    u16*   Sb   = (u16*)ov0;
    float* zfp  = (float*)(ov0 + sbBytes);
    u16*   Vb   = (u16*)alloc((size_t)NROWS * DM * 2);
    u16*   Qp   = (u16*)alloc((size_t)NHROWS * MP * 2);
    u16*   Kp   = (u16*)alloc((size_t)NHROWS * MP * 2);
    u16*   projC= (u16*)alloc((size_t)MP * DH * 2);
    u16*   Wqb  = (u16*)alloc((size_t)DM * DM * 2);
    u16*   Wkb  = (u16*)alloc((size_t)DM * DM * 2);
    u16*   Wvb  = (u16*)alloc((size_t)DM * DM * 2);
    u16*   Wob  = (u16*)alloc((size_t)DM * DM * 2);
    u16*   bqb  = (u16*)alloc(DM * 2);
    u16*   bkb  = (u16*)alloc(DM * 2);
    u16*   bvb  = (u16*)alloc(DM * 2);
    u16*   bob  = (u16*)alloc(DM * 2);
    u32*   flags= (u32*)alloc(16 * 4);
    u32*   gmax = (u32*)alloc(256);
    u32*   gpart= (u32*)alloc(256 * 4);
    float* lstab= (float*)alloc(2048 * 4);
    char*  xatt = alloc((size_t)NROWS * DM * 2);
    u16*   xb   = (u16*)xatt;    // alias: xb dead after gemm_qkv
    u16*   attn = (u16*)xatt;    // scan writes afterwards

    DetectArgs da;
    for (int i = 0; i < 10; ++i) {
        int n = in_sizes[i];
        int nwords = n / 2; if (nwords > 4096) nwords = 4096;
        da.p[i] = (const u32*)d_in[i];
        da.nw[i] = nwords;
    }
    detect_all<<<10, 256, 0, stream>>>(da, flags);

    ConvAllArgs ca;
    ca.xs = x;  ca.xd = xb;
    ca.wsrc[0] = Wq; ca.wsrc[1] = Wk; ca.wsrc[2] = Wv; ca.wsrc[3] = Wo;
    ca.wdst[0] = Wqb; ca.wdst[1] = Wkb; ca.wdst[2] = Wvb; ca.wdst[3] = Wob;
    ca.bsrc[0] = bq; ca.bsrc[1] = bk; ca.bsrc[2] = bv; ca.bsrc[3] = bo;
    ca.bdst[0] = bqb; ca.bdst[1] = bkb; ca.bdst[2] = bvb; ca.bdst[3] = bob;
    ca.pj = proj; ca.pjd = projC;
    ca.gpart = gpart; ca.gmax = gmax; ca.flags = flags;
    conv_all<<<6158, 256, 0, stream>>>(ca);

    dim3 gq(NROWS / 128, DM / 128, 3);
    gemm_qkv<<<gq, 256, 0, stream>>>(xb, Wqb, Wkb, Wvb, bqb, bkb, bvb,
                                     Vb, Qh, Ql, Kh, Kl);

    // fused Q-feat + K-feat (hi/lo bf16 planes in); global max via gpart
    feat_qk<<<4096, 256, 0, stream>>>(Qh, Ql, Kh, Kl, projC, Qp, Kp, gpart, lstab);
    gmax_reduce<<<1, 256, 0, stream>>>(gpart, gmax);

    // MFMA chunk-parallel causal scan; K global-rescale folded into staging
    chunk_ST<<<B_ * H_ * NC, 256, 0, stream>>>(Kp, Vb, Sb, zfp, lstab, gmax);
    chunk_prefix<<<297, 256, 0, stream>>>(Sb, zfp);
    scan_mfma<<<B_ * H_ * NC, 256, 0, stream>>>(Qp, Kp, Vb, Sb, zfp, lstab, gmax, attn);

    // OUTPUT IS FP32 (reference's output dtype, per harness instructions).
    gemm_nt<<<512, 256, 0, stream>>>(attn, Wob, bob, (float*)d_out);
}